// Round 1
// baseline (820.508 us; speedup 1.0000x reference)
//
#include <hip/hip_runtime.h>
#include <math.h>

#define NN 50000
#define NE 800000
#define NG 256
#define IND 128
#define HID 64
#define HEADS 4

__device__ __forceinline__ float lrelu(float x) { return x > 0.f ? x : 0.2f * x; }

// ---------------- GEMM1: feat1 = h @ W1 ([NN,128]x[128,256]) + el1/er1 epilogue ----------------
#define NPB1 8
__global__ __launch_bounds__(256) void k_gemm1(const float* __restrict__ h,
                                               const float* __restrict__ W1,
                                               const float* __restrict__ al,
                                               const float* __restrict__ ar,
                                               float* __restrict__ feat1,
                                               float* __restrict__ el1,
                                               float* __restrict__ er1) {
  __shared__ float hs[NPB1][IND];
  int b0 = blockIdx.x * NPB1;
  int t = threadIdx.x;
  for (int i = t; i < NPB1 * IND; i += 256) {
    int node = b0 + i / IND;
    hs[i / IND][i % IND] = (node < NN) ? h[(size_t)node * IND + (i % IND)] : 0.f;
  }
  __syncthreads();
  float acc[NPB1];
#pragma unroll
  for (int j = 0; j < NPB1; j++) acc[j] = 0.f;
  for (int k = 0; k < IND; k++) {
    float wv = W1[k * 256 + t];
#pragma unroll
    for (int j = 0; j < NPB1; j++) acc[j] += hs[j][k] * wv;
  }
  float alv = al[t], arv = ar[t];
  int lane = t & 63;
  int head = t >> 6;  // 4 waves = 4 heads
#pragma unroll
  for (int j = 0; j < NPB1; j++) {
    int node = b0 + j;
    if (node >= NN) break;
    feat1[(size_t)node * 256 + t] = acc[j];
    float e_l = acc[j] * alv, e_r = acc[j] * arv;
#pragma unroll
    for (int o = 32; o; o >>= 1) { e_l += __shfl_xor(e_l, o); e_r += __shfl_xor(e_r, o); }
    if (lane == 0) { el1[node * 4 + head] = e_l; er1[node * 4 + head] = e_r; }
  }
}

// ---------------- CSR build ----------------
__global__ void k_count(const int* __restrict__ dst, int* __restrict__ counts) {
  int e = blockIdx.x * blockDim.x + threadIdx.x;
  if (e < NE) atomicAdd(&counts[dst[e]], 1);
}

#define SCAN_CHUNK 49
__global__ __launch_bounds__(1024) void k_scan(const int* __restrict__ counts, int* __restrict__ offs) {
  __shared__ int part[1024];
  int tid = threadIdx.x;
  int c0 = tid * SCAN_CHUNK;
  int s = 0;
  for (int i = 0; i < SCAN_CHUNK; i++) {
    int idx = c0 + i;
    if (idx < NN) s += counts[idx];
  }
  part[tid] = s;
  __syncthreads();
  for (int off = 1; off < 1024; off <<= 1) {
    int v = (tid >= off) ? part[tid - off] : 0;
    __syncthreads();
    part[tid] += v;
    __syncthreads();
  }
  int excl = (tid == 0) ? 0 : part[tid - 1];
  for (int i = 0; i < SCAN_CHUNK; i++) {
    int idx = c0 + i;
    if (idx < NN) { offs[idx] = excl; excl += counts[idx]; }
  }
}

__global__ void k_scatter(const int* __restrict__ dst, const int* __restrict__ offs,
                          int* __restrict__ cursor, int* __restrict__ eid) {
  int e = blockIdx.x * blockDim.x + threadIdx.x;
  if (e >= NE) return;
  int d = dst[e];
  int p = atomicAdd(&cursor[d], 1);
  eid[offs[d] + p] = e;
}

// ---------------- edge scores layer 1 ----------------
__global__ void k_edge1(const int* __restrict__ src, const int* __restrict__ dst,
                        const float* __restrict__ el, const float* __restrict__ er,
                        float* __restrict__ ee) {
  int e = blockIdx.x * blockDim.x + threadIdx.x;
  if (e >= NE) return;
  int s = src[e], d = dst[e];
  float4 l = ((const float4*)el)[s];
  float4 r = ((const float4*)er)[d];
  float4 o;
  o.x = expf(lrelu(l.x + r.x));
  o.y = expf(lrelu(l.y + r.y));
  o.z = expf(lrelu(l.z + r.z));
  o.w = expf(lrelu(l.w + r.w));
  ((float4*)ee)[e] = o;
}

// ---------------- aggregation layer 1 (wave per node, fused softmax-div + bias + relu) ----------------
__global__ __launch_bounds__(256) void k_agg1(const int* __restrict__ offs, const int* __restrict__ counts,
                                              const int* __restrict__ eid, const int* __restrict__ src,
                                              const float* __restrict__ ee, const float* __restrict__ feat1,
                                              const float* __restrict__ b1, float* __restrict__ x1) {
  int wid = (blockIdx.x * 256 + threadIdx.x) >> 6;
  int lane = threadIdx.x & 63;
  if (wid >= NN) return;
  int start = offs[wid], cnt = counts[wid];
  float a0 = 0, a1 = 0, a2 = 0, a3 = 0, d0 = 0, d1 = 0, d2 = 0, d3 = 0;
  for (int i = 0; i < cnt; i++) {
    int e = eid[start + i];
    int s = src[e];
    float4 wv = ((const float4*)ee)[e];
    const float* f = feat1 + (size_t)s * 256;
    a0 += wv.x * f[lane];
    a1 += wv.y * f[64 + lane];
    a2 += wv.z * f[128 + lane];
    a3 += wv.w * f[192 + lane];
    d0 += wv.x; d1 += wv.y; d2 += wv.z; d3 += wv.w;
  }
  size_t base = (size_t)wid * 256;
  x1[base + lane]       = fmaxf(a0 / fmaxf(d0, 1e-9f) + b1[lane], 0.f);
  x1[base + 64 + lane]  = fmaxf(a1 / fmaxf(d1, 1e-9f) + b1[64 + lane], 0.f);
  x1[base + 128 + lane] = fmaxf(a2 / fmaxf(d2, 1e-9f) + b1[128 + lane], 0.f);
  x1[base + 192 + lane] = fmaxf(a3 / fmaxf(d3, 1e-9f) + b1[192 + lane], 0.f);
}

// ---------------- GEMM2: feat2 = x1 @ W2 ([NN,256]x[256,64]) + el2/er2 epilogue ----------------
__global__ __launch_bounds__(256) void k_gemm2(const float* __restrict__ x1, const float* __restrict__ W2,
                                               const float* __restrict__ al, const float* __restrict__ ar,
                                               float* __restrict__ feat2, float* __restrict__ el2,
                                               float* __restrict__ er2) {
  extern __shared__ float smem[];
  float* w2s = smem;          // 256*64
  float* xs = smem + 256 * 64;  // 4*256
  int t = threadIdx.x;
  for (int i = t; i < 256 * 64; i += 256) w2s[i] = W2[i];
  int sub = t >> 6, lane = t & 63;
  for (int g0 = blockIdx.x * 4; g0 < NN; g0 += gridDim.x * 4) {
    __syncthreads();
    for (int i = t; i < 4 * 256; i += 256) {
      int node = g0 + i / 256;
      xs[i] = (node < NN) ? x1[(size_t)node * 256 + (i % 256)] : 0.f;
    }
    __syncthreads();
    int node = g0 + sub;
    float acc = 0.f;
#pragma unroll 8
    for (int k = 0; k < 256; k++) acc += xs[sub * 256 + k] * w2s[k * 64 + lane];
    if (node < NN) {
      feat2[(size_t)node * 64 + lane] = acc;
      float e_l = acc * al[lane], e_r = acc * ar[lane];
#pragma unroll
      for (int o = 32; o; o >>= 1) { e_l += __shfl_xor(e_l, o); e_r += __shfl_xor(e_r, o); }
      if (lane == 0) { el2[node] = e_l; er2[node] = e_r; }
    }
  }
}

// ---------------- edge scores layer 2 ----------------
__global__ void k_edge2(const int* __restrict__ src, const int* __restrict__ dst,
                        const float* __restrict__ el, const float* __restrict__ er,
                        float* __restrict__ ee) {
  int e = blockIdx.x * blockDim.x + threadIdx.x;
  if (e >= NE) return;
  ee[e] = expf(lrelu(el[src[e]] + er[dst[e]]));
}

// ---------------- aggregation layer 2 ----------------
__global__ __launch_bounds__(256) void k_agg2(const int* __restrict__ offs, const int* __restrict__ counts,
                                              const int* __restrict__ eid, const int* __restrict__ src,
                                              const float* __restrict__ ee, const float* __restrict__ feat2,
                                              const float* __restrict__ b2, float* __restrict__ x2) {
  int wid = (blockIdx.x * 256 + threadIdx.x) >> 6;
  int lane = threadIdx.x & 63;
  if (wid >= NN) return;
  int start = offs[wid], cnt = counts[wid];
  float acc = 0.f, dsum = 0.f;
  for (int i = 0; i < cnt; i++) {
    int e = eid[start + i];
    int s = src[e];
    float wv = ee[e];
    acc += wv * feat2[(size_t)s * 64 + lane];
    dsum += wv;
  }
  x2[(size_t)wid * 64 + lane] = fmaxf(acc / fmaxf(dsum, 1e-9f) + b2[lane], 0.f);
}

// ---------------- pooling ----------------
__global__ __launch_bounds__(256) void k_pool(const float* __restrict__ x2, const int* __restrict__ gid,
                                              float* __restrict__ psum, int* __restrict__ pcnt) {
  int wid = (blockIdx.x * 256 + threadIdx.x) >> 6;
  int lane = threadIdx.x & 63;
  if (wid >= NN) return;
  int g = gid[wid];
  atomicAdd(&psum[g * 64 + lane], x2[(size_t)wid * 64 + lane]);
  if (lane == 0) atomicAdd(&pcnt[g], 1);
}

// ---------------- classifier head ----------------
__global__ __launch_bounds__(256) void k_head(const float* __restrict__ psum, const int* __restrict__ pcnt,
                                              const float* __restrict__ Wc, const float* __restrict__ bc,
                                              float* __restrict__ out) {
  int g = blockIdx.x * blockDim.x + threadIdx.x;
  if (g >= NG) return;
  float inv = 1.f / fmaxf((float)pcnt[g], 1.f);
  float a0 = bc[0], a1 = bc[1];
  for (int d = 0; d < 64; d++) {
    float p = psum[g * 64 + d] * inv;
    a0 += p * Wc[d * 2 + 0];
    a1 += p * Wc[d * 2 + 1];
  }
  out[g * 2 + 0] = a0;
  out[g * 2 + 1] = a1;
}

extern "C" void kernel_launch(void* const* d_in, const int* in_sizes, int n_in,
                              void* d_out, int out_size, void* d_ws, size_t ws_size,
                              hipStream_t stream) {
  const float* h = (const float*)d_in[0];
  const int* src = (const int*)d_in[1];
  const int* dst = (const int*)d_in[2];
  const int* gid = (const int*)d_in[3];
  const float* W1 = (const float*)d_in[4];
  const float* al1 = (const float*)d_in[5];
  const float* ar1 = (const float*)d_in[6];
  const float* b1 = (const float*)d_in[7];
  const float* W2 = (const float*)d_in[8];
  const float* al2 = (const float*)d_in[9];
  const float* ar2 = (const float*)d_in[10];
  const float* b2 = (const float*)d_in[11];
  const float* Wc = (const float*)d_in[12];
  const float* bc = (const float*)d_in[13];
  float* out = (float*)d_out;

  char* w = (char*)d_ws;
  size_t off = 0;
  auto take = [&](size_t bytes) -> void* {
    void* p = w + off;
    off = (off + bytes + 255) & ~(size_t)255;
    return p;
  };
  float* feat1 = (float*)take((size_t)NN * 256 * 4);  // 51.2 MB
  float* feat2 = feat1;                               // alias (feat1 dead after agg1)
  float* x2 = feat1 + (size_t)NN * 64;                // alias, next 12.8MB inside feat1 region
  float* x1 = (float*)take((size_t)NN * 256 * 4);     // 51.2 MB
  float* ee1 = (float*)take((size_t)NE * 4 * 4);      // 12.8 MB
  float* ee2 = ee1;                                   // alias (ee1 dead after agg1)
  float* el1 = (float*)take((size_t)NN * 4 * 4);
  float* er1 = (float*)take((size_t)NN * 4 * 4);
  float* el2 = (float*)take((size_t)NN * 4);
  float* er2 = (float*)take((size_t)NN * 4);
  int* counts = (int*)take((size_t)NN * 4);
  int* offs = (int*)take((size_t)NN * 4);
  int* cursor = (int*)take((size_t)NN * 4);
  int* eid = (int*)take((size_t)NE * 4);
  float* psum = (float*)take((size_t)NG * 64 * 4);
  int* pcnt = (int*)take((size_t)NG * 4);

  // per-call zeroing of atomically-accumulated buffers
  hipMemsetAsync(counts, 0, (size_t)NN * 4, stream);
  hipMemsetAsync(cursor, 0, (size_t)NN * 4, stream);
  hipMemsetAsync(psum, 0, (size_t)NG * 64 * 4, stream);
  hipMemsetAsync(pcnt, 0, (size_t)NG * 4, stream);

  // CSR build
  k_count<<<(NE + 255) / 256, 256, 0, stream>>>(dst, counts);
  k_scan<<<1, 1024, 0, stream>>>(counts, offs);
  k_scatter<<<(NE + 255) / 256, 256, 0, stream>>>(dst, offs, cursor, eid);

  // layer 1
  k_gemm1<<<(NN + NPB1 - 1) / NPB1, 256, 0, stream>>>(h, W1, al1, ar1, feat1, el1, er1);
  k_edge1<<<(NE + 255) / 256, 256, 0, stream>>>(src, dst, el1, er1, ee1);
  k_agg1<<<(NN * 64 + 255) / 256, 256, 0, stream>>>(offs, counts, eid, src, ee1, feat1, b1, x1);

  // layer 2
  k_gemm2<<<2048, 256, (256 * 64 + 4 * 256) * 4, stream>>>(x1, W2, al2, ar2, feat2, el2, er2);
  k_edge2<<<(NE + 255) / 256, 256, 0, stream>>>(src, dst, el2, er2, ee2);
  k_agg2<<<(NN * 64 + 255) / 256, 256, 0, stream>>>(offs, counts, eid, src, ee2, feat2, b2, x2);

  // pool + head
  k_pool<<<(NN * 64 + 255) / 256, 256, 0, stream>>>(x2, gid, psum, pcnt);
  k_head<<<1, 256, 0, stream>>>(psum, pcnt, Wc, bc, out);
}

// Round 2
// 430.979 us; speedup vs baseline: 1.9038x; 1.9038x over previous
//
#include <hip/hip_runtime.h>
#include <math.h>

#define NN 50000
#define NE 800000
#define NG 256
#define IND 128

typedef __bf16 bf16_t;
typedef bf16_t bf16x8 __attribute__((ext_vector_type(8)));
typedef float f32x4 __attribute__((ext_vector_type(4)));

__device__ __forceinline__ float lrelu(float x) { return fmaxf(x, 0.2f * x); }
__device__ __forceinline__ float b2f(unsigned short u) {
  return __uint_as_float(((unsigned)u) << 16);
}
__device__ __forceinline__ unsigned short f2b(float f) {
  unsigned u = __float_as_uint(f);
  return (unsigned short)((u + 0x7fffu + ((u >> 16) & 1u)) >> 16);
}

// ---------------- GEMM1: feat1 = h @ W1  ([NN,128]x[128,256]) fp32 register-blocked ----------------
// block: 16 nodes, 256 threads. wave w: nodes 4w..4w+3, lane = dim d (0..63), 4 head-cols each.
// feat1b layout: [node][dim d][head] bf16 -> ushort4 per (node,d). el1/er1: float4 per node.
__global__ __launch_bounds__(256) void k_gemm1(const float* __restrict__ h,
                                               const float* __restrict__ W1,
                                               const float* __restrict__ al,
                                               const float* __restrict__ ar,
                                               ushort4* __restrict__ feat1b,
                                               float4* __restrict__ el1,
                                               float4* __restrict__ er1) {
  __shared__ float hs[16][IND];   // 8 KB
  __shared__ float ws[32][256];   // 32 KB
  int t = threadIdx.x;
  int b0 = blockIdx.x * 16;
  for (int i = t; i < 512; i += 256) {  // 16*128 floats = 512 float4
    int n = i >> 5, c = i & 31;
    int gn = b0 + n;
    float4 v = make_float4(0.f, 0.f, 0.f, 0.f);
    if (gn < NN) v = ((const float4*)(h + (size_t)gn * IND))[c];
    ((float4*)hs[n])[c] = v;
  }
  int w = t >> 6, lane = t & 63;
  float acc[4][4] = {};
  for (int kt = 0; kt < IND; kt += 32) {
    __syncthreads();
    for (int i = t; i < 2048; i += 256) {  // 32*256 floats = 2048 float4
      int k = i >> 6, c = i & 63;
      ((float4*)ws[k])[c] = ((const float4*)(W1 + (size_t)(kt + k) * 256))[c];
    }
    __syncthreads();
#pragma unroll
    for (int kk = 0; kk < 32; kk += 4) {
      float4 hv[4];
#pragma unroll
      for (int nl = 0; nl < 4; nl++) hv[nl] = *(const float4*)&hs[w * 4 + nl][kt + kk];
#pragma unroll
      for (int j = 0; j < 4; j++) {
        float wv0 = ws[kk + j][lane];
        float wv1 = ws[kk + j][64 + lane];
        float wv2 = ws[kk + j][128 + lane];
        float wv3 = ws[kk + j][192 + lane];
#pragma unroll
        for (int nl = 0; nl < 4; nl++) {
          float hj = ((const float*)&hv[nl])[j];
          acc[nl][0] += hj * wv0;
          acc[nl][1] += hj * wv1;
          acc[nl][2] += hj * wv2;
          acc[nl][3] += hj * wv3;
        }
      }
    }
  }
  // epilogue
#pragma unroll
  for (int nl = 0; nl < 4; nl++) {
    int gn = b0 + w * 4 + nl;
    if (gn >= NN) break;
    ushort4 fv;
    fv.x = f2b(acc[nl][0]); fv.y = f2b(acc[nl][1]);
    fv.z = f2b(acc[nl][2]); fv.w = f2b(acc[nl][3]);
    feat1b[(size_t)gn * 64 + lane] = fv;
    float pl[4], pr[4];
#pragma unroll
    for (int hh = 0; hh < 4; hh++) {
      pl[hh] = acc[nl][hh] * al[hh * 64 + lane];
      pr[hh] = acc[nl][hh] * ar[hh * 64 + lane];
    }
#pragma unroll
    for (int off = 32; off; off >>= 1) {
#pragma unroll
      for (int hh = 0; hh < 4; hh++) {
        pl[hh] += __shfl_xor(pl[hh], off);
        pr[hh] += __shfl_xor(pr[hh], off);
      }
    }
    if (lane == 0) {
      el1[gn] = make_float4(pl[0], pl[1], pl[2], pl[3]);
      er1[gn] = make_float4(pr[0], pr[1], pr[2], pr[3]);
    }
  }
}

// ---------------- CSR build ----------------
__global__ void k_count(const int* __restrict__ dst, int* __restrict__ counts) {
  int e = blockIdx.x * blockDim.x + threadIdx.x;
  if (e < NE) atomicAdd(&counts[dst[e]], 1);
}

#define SCAN_CHUNK 49
__global__ __launch_bounds__(1024) void k_scan(const int* __restrict__ counts, int* __restrict__ offs) {
  __shared__ int part[1024];
  int tid = threadIdx.x;
  int c0 = tid * SCAN_CHUNK;
  int s = 0;
  for (int i = 0; i < SCAN_CHUNK; i++) {
    int idx = c0 + i;
    if (idx < NN) s += counts[idx];
  }
  part[tid] = s;
  __syncthreads();
  for (int off = 1; off < 1024; off <<= 1) {
    int v = (tid >= off) ? part[tid - off] : 0;
    __syncthreads();
    part[tid] += v;
    __syncthreads();
  }
  int excl = (tid == 0) ? 0 : part[tid - 1];
  for (int i = 0; i < SCAN_CHUNK; i++) {
    int idx = c0 + i;
    if (idx < NN) { offs[idx] = excl; excl += counts[idx]; }
  }
  if (tid == 0) offs[NN] = NE;
}

// scatter: build dst-sorted source-index array (no eid indirection needed later)
__global__ void k_scatter(const int* __restrict__ src, const int* __restrict__ dst,
                          const int* __restrict__ offs, int* __restrict__ cursor,
                          int* __restrict__ srcs) {
  int e = blockIdx.x * blockDim.x + threadIdx.x;
  if (e >= NE) return;
  int d = dst[e];
  int p = atomicAdd(&cursor[d], 1);
  srcs[offs[d] + p] = src[e];
}

// ---------------- aggregation layer 1 (wave/node; inline edge-softmax; bf16 gather) ----------------
__global__ __launch_bounds__(256) void k_agg1(const int* __restrict__ offs, const int* __restrict__ srcs,
                                              const float4* __restrict__ el1, const float4* __restrict__ er1,
                                              const ushort4* __restrict__ feat1b,
                                              const float* __restrict__ b1,
                                              unsigned short* __restrict__ x1b) {
  int wid = (blockIdx.x * 256 + threadIdx.x) >> 6;
  int lane = threadIdx.x & 63;
  if (wid >= NN) return;
  int i = offs[wid], end = offs[wid + 1];
  float4 er = er1[wid];
  float a0 = 0, a1 = 0, a2 = 0, a3 = 0, d0 = 0, d1 = 0, d2 = 0, d3 = 0;
  for (; i + 2 <= end; i += 2) {
    int s0 = srcs[i], s1 = srcs[i + 1];
    float4 l0 = el1[s0], l1 = el1[s1];
    ushort4 f0 = feat1b[(size_t)s0 * 64 + lane];
    ushort4 f1 = feat1b[(size_t)s1 * 64 + lane];
    float w0x = __expf(lrelu(l0.x + er.x)), w0y = __expf(lrelu(l0.y + er.y));
    float w0z = __expf(lrelu(l0.z + er.z)), w0w = __expf(lrelu(l0.w + er.w));
    float w1x = __expf(lrelu(l1.x + er.x)), w1y = __expf(lrelu(l1.y + er.y));
    float w1z = __expf(lrelu(l1.z + er.z)), w1w = __expf(lrelu(l1.w + er.w));
    a0 += w0x * b2f(f0.x) + w1x * b2f(f1.x);
    a1 += w0y * b2f(f0.y) + w1y * b2f(f1.y);
    a2 += w0z * b2f(f0.z) + w1z * b2f(f1.z);
    a3 += w0w * b2f(f0.w) + w1w * b2f(f1.w);
    d0 += w0x + w1x; d1 += w0y + w1y; d2 += w0z + w1z; d3 += w0w + w1w;
  }
  if (i < end) {
    int s0 = srcs[i];
    float4 l0 = el1[s0];
    ushort4 f0 = feat1b[(size_t)s0 * 64 + lane];
    float w0x = __expf(lrelu(l0.x + er.x)), w0y = __expf(lrelu(l0.y + er.y));
    float w0z = __expf(lrelu(l0.z + er.z)), w0w = __expf(lrelu(l0.w + er.w));
    a0 += w0x * b2f(f0.x); a1 += w0y * b2f(f0.y);
    a2 += w0z * b2f(f0.z); a3 += w0w * b2f(f0.w);
    d0 += w0x; d1 += w0y; d2 += w0z; d3 += w0w;
  }
  size_t base = (size_t)wid * 256;
  x1b[base + lane]        = f2b(fmaxf(a0 / fmaxf(d0, 1e-9f) + b1[lane], 0.f));
  x1b[base + 64 + lane]   = f2b(fmaxf(a1 / fmaxf(d1, 1e-9f) + b1[64 + lane], 0.f));
  x1b[base + 128 + lane]  = f2b(fmaxf(a2 / fmaxf(d2, 1e-9f) + b1[128 + lane], 0.f));
  x1b[base + 192 + lane]  = f2b(fmaxf(a3 / fmaxf(d3, 1e-9f) + b1[192 + lane], 0.f));
}

// ---------------- GEMM2 (MFMA bf16): feat2 = x1 @ W2 ([NN,256]x[256,64]) + el2/er2 ----------------
// block = 64 nodes, 4 waves; wave w: 16-row tile. B (W2 bf16) transposed+swizzled in LDS.
__global__ __launch_bounds__(256) void k_gemm2(const unsigned short* __restrict__ x1b,
                                               const float* __restrict__ W2,
                                               const float* __restrict__ al2,
                                               const float* __restrict__ ar2,
                                               unsigned short* __restrict__ feat2b,
                                               float* __restrict__ el2,
                                               float* __restrict__ er2) {
  __shared__ unsigned short w2t[64 * 256];  // 32 KB, [col][k] swizzled
  int t = threadIdx.x;
  for (int i = t; i < 64 * 256; i += 256) {  // i = k*64+col (coalesced W2 read)
    int k = i >> 6, col = i & 63;
    int kg = k >> 3;
    int s = (col * 32 + kg) ^ (col & 7);
    w2t[s * 8 + (k & 7)] = f2b(W2[i]);
  }
  __syncthreads();
  int w = t >> 6, l = t & 63;
  int rw = blockIdx.x * 64 + w * 16;
  int arow = rw + (l & 15);
  if (arow >= NN) arow = NN - 1;  // clamp loads; stores guarded
  const unsigned short* aptr = x1b + (size_t)arow * 256 + (l >> 4) * 8;
  f32x4 acc[4] = {};
#pragma unroll
  for (int ks = 0; ks < 8; ks++) {
    bf16x8 a = *(const bf16x8*)(const void*)(aptr + ks * 32);
#pragma unroll
    for (int n = 0; n < 4; n++) {
      int colg = n * 16 + (l & 15);
      int kg = ks * 4 + (l >> 4);
      int s = (colg * 32 + kg) ^ (colg & 7);
      bf16x8 b = *(const bf16x8*)(const void*)&w2t[s * 8];
      acc[n] = __builtin_amdgcn_mfma_f32_16x16x32_bf16(a, b, acc[n], 0, 0, 0);
    }
  }
  // epilogue: C layout col=lane&15, row=(lane>>4)*4+reg
  float al2v[4], ar2v[4];
#pragma unroll
  for (int n = 0; n < 4; n++) { al2v[n] = al2[n * 16 + (l & 15)]; ar2v[n] = ar2[n * 16 + (l & 15)]; }
#pragma unroll
  for (int j = 0; j < 4; j++) {
    int node = rw + (l >> 4) * 4 + j;
    float pl = 0.f, pr = 0.f;
#pragma unroll
    for (int n = 0; n < 4; n++) {
      float c = acc[n][j];
      if (node < NN) feat2b[(size_t)node * 64 + n * 16 + (l & 15)] = f2b(c);
      pl += c * al2v[n];
      pr += c * ar2v[n];
    }
#pragma unroll
    for (int off = 1; off < 16; off <<= 1) {
      pl += __shfl_xor(pl, off);
      pr += __shfl_xor(pr, off);
    }
    if ((l & 15) == 0 && node < NN) { el2[node] = pl; er2[node] = pr; }
  }
}

// ---------------- aggregation layer 2 + fused mean-pool atomics ----------------
__global__ __launch_bounds__(256) void k_agg2(const int* __restrict__ offs, const int* __restrict__ srcs,
                                              const float* __restrict__ el2, const float* __restrict__ er2,
                                              const unsigned short* __restrict__ feat2b,
                                              const float* __restrict__ b2, const int* __restrict__ gid,
                                              float* __restrict__ psum) {
  int wid = (blockIdx.x * 256 + threadIdx.x) >> 6;
  int lane = threadIdx.x & 63;
  if (wid >= NN) return;
  int i = offs[wid], end = offs[wid + 1];
  float erv = er2[wid];
  float acc = 0.f, dsum = 0.f;
  for (; i + 2 <= end; i += 2) {
    int s0 = srcs[i], s1 = srcs[i + 1];
    float w0 = __expf(lrelu(el2[s0] + erv));
    float w1 = __expf(lrelu(el2[s1] + erv));
    float f0 = b2f(feat2b[(size_t)s0 * 64 + lane]);
    float f1 = b2f(feat2b[(size_t)s1 * 64 + lane]);
    acc += w0 * f0 + w1 * f1;
    dsum += w0 + w1;
  }
  if (i < end) {
    int s0 = srcs[i];
    float w0 = __expf(lrelu(el2[s0] + erv));
    acc += w0 * b2f(feat2b[(size_t)s0 * 64 + lane]);
    dsum += w0;
  }
  float v = fmaxf(acc / fmaxf(dsum, 1e-9f) + b2[lane], 0.f);
  atomicAdd(&psum[gid[wid] * 64 + lane], v);
}

// ---------------- classifier head (counts via binary search on sorted gid) ----------------
__global__ __launch_bounds__(256) void k_head(const float* __restrict__ psum, const int* __restrict__ gid,
                                              const float* __restrict__ Wc, const float* __restrict__ bc,
                                              float* __restrict__ out) {
  int wid = (blockIdx.x * 256 + threadIdx.x) >> 6;
  int lane = threadIdx.x & 63;
  if (wid >= NG) return;
  int g = wid;
  int lo = 0, hi = NN;
  while (lo < hi) { int mid = (lo + hi) >> 1; if (gid[mid] < g) lo = mid + 1; else hi = mid; }
  int lb = lo;
  hi = NN;
  while (lo < hi) { int mid = (lo + hi) >> 1; if (gid[mid] < g + 1) lo = mid + 1; else hi = mid; }
  int cnt = lo - lb;
  float inv = 1.f / fmaxf((float)cnt, 1.f);
  float p = psum[g * 64 + lane] * inv;
  float a0 = p * Wc[lane * 2 + 0];
  float a1 = p * Wc[lane * 2 + 1];
#pragma unroll
  for (int off = 32; off; off >>= 1) { a0 += __shfl_xor(a0, off); a1 += __shfl_xor(a1, off); }
  if (lane == 0) { out[g * 2 + 0] = a0 + bc[0]; out[g * 2 + 1] = a1 + bc[1]; }
}

extern "C" void kernel_launch(void* const* d_in, const int* in_sizes, int n_in,
                              void* d_out, int out_size, void* d_ws, size_t ws_size,
                              hipStream_t stream) {
  const float* h = (const float*)d_in[0];
  const int* src = (const int*)d_in[1];
  const int* dst = (const int*)d_in[2];
  const int* gid = (const int*)d_in[3];
  const float* W1 = (const float*)d_in[4];
  const float* al1 = (const float*)d_in[5];
  const float* ar1 = (const float*)d_in[6];
  const float* b1 = (const float*)d_in[7];
  const float* W2 = (const float*)d_in[8];
  const float* al2 = (const float*)d_in[9];
  const float* ar2 = (const float*)d_in[10];
  const float* b2 = (const float*)d_in[11];
  const float* Wc = (const float*)d_in[12];
  const float* bc = (const float*)d_in[13];
  float* out = (float*)d_out;

  char* wsp = (char*)d_ws;
  size_t off = 0;
  auto take = [&](size_t bytes) -> void* {
    void* p = wsp + off;
    off = (off + bytes + 255) & ~(size_t)255;
    return p;
  };
  ushort4* feat1b = (ushort4*)take((size_t)NN * 256 * 2);        // 25.6 MB
  unsigned short* x1b = (unsigned short*)take((size_t)NN * 256 * 2);  // 25.6 MB
  unsigned short* feat2b = (unsigned short*)take((size_t)NN * 64 * 2);  // 6.4 MB
  float4* el1 = (float4*)take((size_t)NN * 16);
  float4* er1 = (float4*)take((size_t)NN * 16);
  float* el2 = (float*)take((size_t)NN * 4);
  float* er2 = (float*)take((size_t)NN * 4);
  int* counts = (int*)take((size_t)NN * 4);
  int* offs = (int*)take((size_t)(NN + 1) * 4);
  int* cursor = (int*)take((size_t)NN * 4);
  int* srcs = (int*)take((size_t)NE * 4);
  float* psum = (float*)take((size_t)NG * 64 * 4);

  hipMemsetAsync(counts, 0, (size_t)NN * 4, stream);
  hipMemsetAsync(cursor, 0, (size_t)NN * 4, stream);
  hipMemsetAsync(psum, 0, (size_t)NG * 64 * 4, stream);

  // CSR build
  k_count<<<(NE + 255) / 256, 256, 0, stream>>>(dst, counts);
  k_scan<<<1, 1024, 0, stream>>>(counts, offs);
  k_scatter<<<(NE + 255) / 256, 256, 0, stream>>>(src, dst, offs, cursor, srcs);

  // layer 1
  k_gemm1<<<(NN + 15) / 16, 256, 0, stream>>>(h, W1, al1, ar1, feat1b, el1, er1);
  k_agg1<<<(NN * 64 + 255) / 256, 256, 0, stream>>>(offs, srcs, el1, er1, feat1b, b1, x1b);

  // layer 2
  k_gemm2<<<(NN + 63) / 64, 256, 0, stream>>>(x1b, W2, al2, ar2, feat2b, el2, er2);
  k_agg2<<<(NN * 64 + 255) / 256, 256, 0, stream>>>(offs, srcs, el2, er2, feat2b, b2, gid, psum);

  // head
  k_head<<<(NG * 64 + 255) / 256, 256, 0, stream>>>(psum, gid, Wc, bc, out);
}

// Round 3
// 382.947 us; speedup vs baseline: 2.1426x; 1.1254x over previous
//
#include <hip/hip_runtime.h>
#include <math.h>

#define NN 50000
#define NE 800000
#define NG 256
#define IND 128

typedef __bf16 bf16_t;
typedef bf16_t bf16x8 __attribute__((ext_vector_type(8)));
typedef float f32x4 __attribute__((ext_vector_type(4)));
typedef unsigned short ushortx8 __attribute__((ext_vector_type(8)));

__device__ __forceinline__ float lrelu(float x) { return fmaxf(x, 0.2f * x); }
__device__ __forceinline__ float b2f(unsigned short u) {
  return __uint_as_float(((unsigned)u) << 16);
}
__device__ __forceinline__ unsigned short f2b(float f) {
  unsigned u = __float_as_uint(f);
  return (unsigned short)((u + 0x7fffu + ((u >> 16) & 1u)) >> 16);
}

// ---------------- prep: h -> h_hi/h_lo bf16 split; W1 -> transposed bf16 [col][k] ----------------
#define HCHUNKS (NN * IND / 8)  // 800000
__global__ __launch_bounds__(256) void k_prep(const float* __restrict__ h,
                                              const float* __restrict__ W1,
                                              unsigned short* __restrict__ h_hi,
                                              unsigned short* __restrict__ h_lo,
                                              unsigned short* __restrict__ w1t_hi) {
  int tid = blockIdx.x * 256 + threadIdx.x;
  if (tid < HCHUNKS) {
    const float4* p = (const float4*)h + (size_t)tid * 2;
    float4 v0 = p[0], v1 = p[1];
    float f[8] = {v0.x, v0.y, v0.z, v0.w, v1.x, v1.y, v1.z, v1.w};
    ushortx8 hi, lo;
#pragma unroll
    for (int j = 0; j < 8; j++) {
      unsigned short hj = f2b(f[j]);
      hi[j] = hj;
      lo[j] = f2b(f[j] - b2f(hj));
    }
    ((ushortx8*)h_hi)[tid] = hi;
    ((ushortx8*)h_lo)[tid] = lo;
  } else if (tid < HCHUNKS + 256 * IND) {
    int idx = tid - HCHUNKS;  // output [c][k]
    int c = idx >> 7, k = idx & 127;
    w1t_hi[idx] = f2b(W1[(size_t)k * 256 + c]);
  }
}

// ---------------- GEMM1 (MFMA, split-A): feat1 = h @ W1 ([NN,128]x[128,256]) + el1/er1 ----------------
// block = 64 nodes, 4 waves of 16 rows. B (W1^T bf16) in XOR-swizzled LDS, A hi/lo from global.
__global__ __launch_bounds__(256) void k_gemm1(const unsigned short* __restrict__ h_hi,
                                               const unsigned short* __restrict__ h_lo,
                                               const unsigned short* __restrict__ w1t_hi,
                                               const float* __restrict__ al,
                                               const float* __restrict__ ar,
                                               unsigned short* __restrict__ feat1b,
                                               float4* __restrict__ el1,
                                               float4* __restrict__ er1) {
  __shared__ unsigned short w1s[256 * IND];  // 64 KB, [col][k] swizzled
  int t = threadIdx.x;
  for (int i = t; i < 4096; i += 256) {  // 4096 ushort8 chunks
    int c = i >> 4, k8 = i & 15;
    ushortx8 v = ((const ushortx8*)w1t_hi)[i];
    int byte = (c * 256 + k8 * 16) ^ ((c & 7) << 4);
    *(ushortx8*)((char*)w1s + byte) = v;
  }
  __syncthreads();
  int w = t >> 6, l = t & 63;
  int c0 = l & 15, kg = l >> 4;
  int rw = blockIdx.x * 64 + w * 16;
  int arow = rw + c0;
  if (arow >= NN) arow = NN - 1;
  const unsigned short* ahp = h_hi + (size_t)arow * IND + kg * 8;
  const unsigned short* alp = h_lo + (size_t)arow * IND + kg * 8;
  f32x4 acc[16] = {};
#pragma unroll
  for (int ks = 0; ks < 4; ks++) {
    bf16x8 ah = *(const bf16x8*)(const void*)(ahp + ks * 32);
    bf16x8 alo = *(const bf16x8*)(const void*)(alp + ks * 32);
#pragma unroll
    for (int n = 0; n < 16; n++) {
      int col = n * 16 + c0;
      int byte = (col * 256 + (ks * 4 + kg) * 16) ^ ((col & 7) << 4);
      bf16x8 b = *(const bf16x8*)(const void*)((const char*)w1s + byte);
      acc[n] = __builtin_amdgcn_mfma_f32_16x16x32_bf16(alo, b, acc[n], 0, 0, 0);
      acc[n] = __builtin_amdgcn_mfma_f32_16x16x32_bf16(ah, b, acc[n], 0, 0, 0);
    }
  }
  // epilogue: C row = kg*4+j, col = n*16+c0; store feat1b[node][d][h] (d=col&63,h=col>>6)
  float alv[16], arv[16];
#pragma unroll
  for (int n = 0; n < 16; n++) {
    int ai = (n >> 2) * 64 + (n & 3) * 16 + c0;
    alv[n] = al[ai];
    arv[n] = ar[ai];
  }
#pragma unroll
  for (int j = 0; j < 4; j++) {
    int node = rw + kg * 4 + j;
    bool ok = node < NN;
    float pl[4] = {0.f, 0.f, 0.f, 0.f}, pr[4] = {0.f, 0.f, 0.f, 0.f};
#pragma unroll
    for (int n = 0; n < 16; n++) {
      float cv = acc[n][j];
      int hh = n >> 2;
      int d = (n & 3) * 16 + c0;
      if (ok) feat1b[(size_t)node * 256 + d * 4 + hh] = f2b(cv);
      pl[hh] += cv * alv[n];
      pr[hh] += cv * arv[n];
    }
#pragma unroll
    for (int off = 1; off < 16; off <<= 1) {
#pragma unroll
      for (int hh = 0; hh < 4; hh++) {
        pl[hh] += __shfl_xor(pl[hh], off);
        pr[hh] += __shfl_xor(pr[hh], off);
      }
    }
    if (c0 == 0 && ok) {
      el1[node] = make_float4(pl[0], pl[1], pl[2], pl[3]);
      er1[node] = make_float4(pr[0], pr[1], pr[2], pr[3]);
    }
  }
}

// ---------------- CSR build ----------------
__global__ void k_count(const int* __restrict__ dst, int* __restrict__ counts) {
  int e = blockIdx.x * blockDim.x + threadIdx.x;
  if (e < NE) atomicAdd(&counts[dst[e]], 1);
}

#define SCAN_CHUNK 49
__global__ __launch_bounds__(1024) void k_scan(const int* __restrict__ counts, int* __restrict__ offs) {
  __shared__ int part[1024];
  int tid = threadIdx.x;
  int c0 = tid * SCAN_CHUNK;
  int s = 0;
  for (int i = 0; i < SCAN_CHUNK; i++) {
    int idx = c0 + i;
    if (idx < NN) s += counts[idx];
  }
  part[tid] = s;
  __syncthreads();
  for (int off = 1; off < 1024; off <<= 1) {
    int v = (tid >= off) ? part[tid - off] : 0;
    __syncthreads();
    part[tid] += v;
    __syncthreads();
  }
  int excl = (tid == 0) ? 0 : part[tid - 1];
  for (int i = 0; i < SCAN_CHUNK; i++) {
    int idx = c0 + i;
    if (idx < NN) { offs[idx] = excl; excl += counts[idx]; }
  }
  if (tid == 0) offs[NN] = NE;
}

__global__ void k_scatter(const int* __restrict__ src, const int* __restrict__ dst,
                          const int* __restrict__ offs, int* __restrict__ cursor,
                          int* __restrict__ srcs) {
  int e = blockIdx.x * blockDim.x + threadIdx.x;
  if (e >= NE) return;
  int d = dst[e];
  int p = atomicAdd(&cursor[d], 1);
  srcs[offs[d] + p] = src[e];
}

// ---------------- aggregation layer 1 (wave/node; inline edge-softmax; bf16 gather) ----------------
__global__ __launch_bounds__(256) void k_agg1(const int* __restrict__ offs, const int* __restrict__ srcs,
                                              const float4* __restrict__ el1, const float4* __restrict__ er1,
                                              const ushort4* __restrict__ feat1b,
                                              const float* __restrict__ b1,
                                              unsigned short* __restrict__ x1b) {
  int wid = (blockIdx.x * 256 + threadIdx.x) >> 6;
  int lane = threadIdx.x & 63;
  if (wid >= NN) return;
  int i = offs[wid], end = offs[wid + 1];
  float4 er = er1[wid];
  float a0 = 0, a1 = 0, a2 = 0, a3 = 0, d0 = 0, d1 = 0, d2 = 0, d3 = 0;
  for (; i + 2 <= end; i += 2) {
    int s0 = srcs[i], s1 = srcs[i + 1];
    float4 l0 = el1[s0], l1 = el1[s1];
    ushort4 f0 = feat1b[(size_t)s0 * 64 + lane];
    ushort4 f1 = feat1b[(size_t)s1 * 64 + lane];
    float w0x = __expf(lrelu(l0.x + er.x)), w0y = __expf(lrelu(l0.y + er.y));
    float w0z = __expf(lrelu(l0.z + er.z)), w0w = __expf(lrelu(l0.w + er.w));
    float w1x = __expf(lrelu(l1.x + er.x)), w1y = __expf(lrelu(l1.y + er.y));
    float w1z = __expf(lrelu(l1.z + er.z)), w1w = __expf(lrelu(l1.w + er.w));
    a0 += w0x * b2f(f0.x) + w1x * b2f(f1.x);
    a1 += w0y * b2f(f0.y) + w1y * b2f(f1.y);
    a2 += w0z * b2f(f0.z) + w1z * b2f(f1.z);
    a3 += w0w * b2f(f0.w) + w1w * b2f(f1.w);
    d0 += w0x + w1x; d1 += w0y + w1y; d2 += w0z + w1z; d3 += w0w + w1w;
  }
  if (i < end) {
    int s0 = srcs[i];
    float4 l0 = el1[s0];
    ushort4 f0 = feat1b[(size_t)s0 * 64 + lane];
    float w0x = __expf(lrelu(l0.x + er.x)), w0y = __expf(lrelu(l0.y + er.y));
    float w0z = __expf(lrelu(l0.z + er.z)), w0w = __expf(lrelu(l0.w + er.w));
    a0 += w0x * b2f(f0.x); a1 += w0y * b2f(f0.y);
    a2 += w0z * b2f(f0.z); a3 += w0w * b2f(f0.w);
    d0 += w0x; d1 += w0y; d2 += w0z; d3 += w0w;
  }
  size_t base = (size_t)wid * 256;
  x1b[base + lane]        = f2b(fmaxf(a0 / fmaxf(d0, 1e-9f) + b1[lane], 0.f));
  x1b[base + 64 + lane]   = f2b(fmaxf(a1 / fmaxf(d1, 1e-9f) + b1[64 + lane], 0.f));
  x1b[base + 128 + lane]  = f2b(fmaxf(a2 / fmaxf(d2, 1e-9f) + b1[128 + lane], 0.f));
  x1b[base + 192 + lane]  = f2b(fmaxf(a3 / fmaxf(d3, 1e-9f) + b1[192 + lane], 0.f));
}

// ---------------- GEMM2 (MFMA bf16): feat2 = x1 @ W2 ([NN,256]x[256,64]) + el2/er2 ----------------
__global__ __launch_bounds__(256) void k_gemm2(const unsigned short* __restrict__ x1b,
                                               const float* __restrict__ W2,
                                               const float* __restrict__ al2,
                                               const float* __restrict__ ar2,
                                               unsigned short* __restrict__ feat2b,
                                               float* __restrict__ el2,
                                               float* __restrict__ er2) {
  __shared__ unsigned short w2t[64 * 256];  // 32 KB, [col][k] swizzled
  int t = threadIdx.x;
  for (int i = t; i < 64 * 256; i += 256) {  // i = k*64+col (coalesced W2 read)
    int k = i >> 6, col = i & 63;
    int kg = k >> 3;
    int s = (col * 32 + kg) ^ (col & 7);
    w2t[s * 8 + (k & 7)] = f2b(W2[i]);
  }
  __syncthreads();
  int w = t >> 6, l = t & 63;
  int rw = blockIdx.x * 64 + w * 16;
  int arow = rw + (l & 15);
  if (arow >= NN) arow = NN - 1;  // clamp loads; stores guarded
  const unsigned short* aptr = x1b + (size_t)arow * 256 + (l >> 4) * 8;
  f32x4 acc[4] = {};
#pragma unroll
  for (int ks = 0; ks < 8; ks++) {
    bf16x8 a = *(const bf16x8*)(const void*)(aptr + ks * 32);
#pragma unroll
    for (int n = 0; n < 4; n++) {
      int colg = n * 16 + (l & 15);
      int kg = ks * 4 + (l >> 4);
      int s = (colg * 32 + kg) ^ (colg & 7);
      bf16x8 b = *(const bf16x8*)(const void*)&w2t[s * 8];
      acc[n] = __builtin_amdgcn_mfma_f32_16x16x32_bf16(a, b, acc[n], 0, 0, 0);
    }
  }
  float al2v[4], ar2v[4];
#pragma unroll
  for (int n = 0; n < 4; n++) { al2v[n] = al2[n * 16 + (l & 15)]; ar2v[n] = ar2[n * 16 + (l & 15)]; }
#pragma unroll
  for (int j = 0; j < 4; j++) {
    int node = rw + (l >> 4) * 4 + j;
    float pl = 0.f, pr = 0.f;
#pragma unroll
    for (int n = 0; n < 4; n++) {
      float c = acc[n][j];
      if (node < NN) feat2b[(size_t)node * 64 + n * 16 + (l & 15)] = f2b(c);
      pl += c * al2v[n];
      pr += c * ar2v[n];
    }
#pragma unroll
    for (int off = 1; off < 16; off <<= 1) {
      pl += __shfl_xor(pl, off);
      pr += __shfl_xor(pr, off);
    }
    if ((l & 15) == 0 && node < NN) { el2[node] = pl; er2[node] = pr; }
  }
}

// ---------------- aggregation layer 2 + fused mean-pool atomics ----------------
__global__ __launch_bounds__(256) void k_agg2(const int* __restrict__ offs, const int* __restrict__ srcs,
                                              const float* __restrict__ el2, const float* __restrict__ er2,
                                              const unsigned short* __restrict__ feat2b,
                                              const float* __restrict__ b2, const int* __restrict__ gid,
                                              float* __restrict__ psum) {
  int wid = (blockIdx.x * 256 + threadIdx.x) >> 6;
  int lane = threadIdx.x & 63;
  if (wid >= NN) return;
  int i = offs[wid], end = offs[wid + 1];
  float erv = er2[wid];
  float acc = 0.f, dsum = 0.f;
  for (; i + 2 <= end; i += 2) {
    int s0 = srcs[i], s1 = srcs[i + 1];
    float w0 = __expf(lrelu(el2[s0] + erv));
    float w1 = __expf(lrelu(el2[s1] + erv));
    float f0 = b2f(feat2b[(size_t)s0 * 64 + lane]);
    float f1 = b2f(feat2b[(size_t)s1 * 64 + lane]);
    acc += w0 * f0 + w1 * f1;
    dsum += w0 + w1;
  }
  if (i < end) {
    int s0 = srcs[i];
    float w0 = __expf(lrelu(el2[s0] + erv));
    acc += w0 * b2f(feat2b[(size_t)s0 * 64 + lane]);
    dsum += w0;
  }
  float v = fmaxf(acc / fmaxf(dsum, 1e-9f) + b2[lane], 0.f);
  atomicAdd(&psum[gid[wid] * 64 + lane], v);
}

// ---------------- classifier head ----------------
__global__ __launch_bounds__(256) void k_head(const float* __restrict__ psum, const int* __restrict__ gid,
                                              const float* __restrict__ Wc, const float* __restrict__ bc,
                                              float* __restrict__ out) {
  int wid = (blockIdx.x * 256 + threadIdx.x) >> 6;
  int lane = threadIdx.x & 63;
  if (wid >= NG) return;
  int g = wid;
  int lo = 0, hi = NN;
  while (lo < hi) { int mid = (lo + hi) >> 1; if (gid[mid] < g) lo = mid + 1; else hi = mid; }
  int lb = lo;
  hi = NN;
  while (lo < hi) { int mid = (lo + hi) >> 1; if (gid[mid] < g + 1) lo = mid + 1; else hi = mid; }
  int cnt = lo - lb;
  float inv = 1.f / fmaxf((float)cnt, 1.f);
  float p = psum[g * 64 + lane] * inv;
  float a0 = p * Wc[lane * 2 + 0];
  float a1 = p * Wc[lane * 2 + 1];
#pragma unroll
  for (int off = 32; off; off >>= 1) { a0 += __shfl_xor(a0, off); a1 += __shfl_xor(a1, off); }
  if (lane == 0) { out[g * 2 + 0] = a0 + bc[0]; out[g * 2 + 1] = a1 + bc[1]; }
}

extern "C" void kernel_launch(void* const* d_in, const int* in_sizes, int n_in,
                              void* d_out, int out_size, void* d_ws, size_t ws_size,
                              hipStream_t stream) {
  const float* h = (const float*)d_in[0];
  const int* src = (const int*)d_in[1];
  const int* dst = (const int*)d_in[2];
  const int* gid = (const int*)d_in[3];
  const float* W1 = (const float*)d_in[4];
  const float* al1 = (const float*)d_in[5];
  const float* ar1 = (const float*)d_in[6];
  const float* b1 = (const float*)d_in[7];
  const float* W2 = (const float*)d_in[8];
  const float* al2 = (const float*)d_in[9];
  const float* ar2 = (const float*)d_in[10];
  const float* b2 = (const float*)d_in[11];
  const float* Wc = (const float*)d_in[12];
  const float* bc = (const float*)d_in[13];
  float* out = (float*)d_out;

  char* wsp = (char*)d_ws;
  size_t off = 0;
  auto take = [&](size_t bytes) -> void* {
    void* p = wsp + off;
    off = (off + bytes + 255) & ~(size_t)255;
    return p;
  };
  unsigned short* feat1b = (unsigned short*)take((size_t)NN * 256 * 2);   // 25.6 MB
  unsigned short* x1b = (unsigned short*)take((size_t)NN * 256 * 2);      // 25.6 MB
  unsigned short* feat2b = (unsigned short*)take((size_t)NN * 64 * 2);    // 6.4 MB
  unsigned short* h_hi = (unsigned short*)take((size_t)NN * IND * 2);     // 12.8 MB
  unsigned short* h_lo = (unsigned short*)take((size_t)NN * IND * 2);     // 12.8 MB
  unsigned short* w1t_hi = (unsigned short*)take((size_t)256 * IND * 2);  // 64 KB
  float4* el1 = (float4*)take((size_t)NN * 16);
  float4* er1 = (float4*)take((size_t)NN * 16);
  float* el2 = (float*)take((size_t)NN * 4);
  float* er2 = (float*)take((size_t)NN * 4);
  int* counts = (int*)take((size_t)NN * 4);
  int* offs = (int*)take((size_t)(NN + 1) * 4);
  int* cursor = (int*)take((size_t)NN * 4);
  int* srcs = (int*)take((size_t)NE * 4);
  float* psum = (float*)take((size_t)NG * 64 * 4);

  hipMemsetAsync(counts, 0, (size_t)NN * 4, stream);
  hipMemsetAsync(cursor, 0, (size_t)NN * 4, stream);
  hipMemsetAsync(psum, 0, (size_t)NG * 64 * 4, stream);

  // prep (h split + W1 transpose/convert)
  k_prep<<<(HCHUNKS + 256 * IND + 255) / 256, 256, 0, stream>>>(h, W1, h_hi, h_lo, w1t_hi);

  // CSR build
  k_count<<<(NE + 255) / 256, 256, 0, stream>>>(dst, counts);
  k_scan<<<1, 1024, 0, stream>>>(counts, offs);
  k_scatter<<<(NE + 255) / 256, 256, 0, stream>>>(src, dst, offs, cursor, srcs);

  // layer 1
  k_gemm1<<<(NN + 63) / 64, 256, 0, stream>>>(h_hi, h_lo, w1t_hi, al1, ar1, feat1b, el1, er1);
  k_agg1<<<(NN * 64 + 255) / 256, 256, 0, stream>>>(offs, srcs, el1, er1, (const ushort4*)feat1b, b1, x1b);

  // layer 2
  k_gemm2<<<(NN + 63) / 64, 256, 0, stream>>>(x1b, W2, al2, ar2, feat2b, el2, er2);
  k_agg2<<<(NN * 64 + 255) / 256, 256, 0, stream>>>(offs, srcs, el2, er2, feat2b, b2, gid, psum);

  // head
  k_head<<<(NG * 64 + 255) / 256, 256, 0, stream>>>(psum, gid, Wc, bc, out);
}

// Round 4
// 292.458 us; speedup vs baseline: 2.8056x; 1.3094x over previous
//
#include <hip/hip_runtime.h>
#include <math.h>

#define NN 50000
#define NE 800000
#define NG 256
#define IND 128

typedef __bf16 bf16_t;
typedef bf16_t bf16x8 __attribute__((ext_vector_type(8)));
typedef float f32x4 __attribute__((ext_vector_type(4)));
typedef unsigned short ushortx8 __attribute__((ext_vector_type(8)));

__device__ __forceinline__ float lrelu(float x) { return fmaxf(x, 0.2f * x); }
__device__ __forceinline__ float b2f(unsigned short u) {
  return __uint_as_float(((unsigned)u) << 16);
}
__device__ __forceinline__ unsigned short f2b(float f) {
  unsigned u = __float_as_uint(f);
  return (unsigned short)((u + 0x7fffu + ((u >> 16) & 1u)) >> 16);
}

// ---------------- prep: h split; W1 transpose; edge count (fused) ----------------
#define HCHUNKS (NN * IND / 8)  // 800000
__global__ __launch_bounds__(256) void k_prep(const float* __restrict__ h,
                                              const float* __restrict__ W1,
                                              const int* __restrict__ dst,
                                              unsigned short* __restrict__ h_hi,
                                              unsigned short* __restrict__ h_lo,
                                              unsigned short* __restrict__ w1t_hi,
                                              int* __restrict__ counts) {
  int tid = blockIdx.x * 256 + threadIdx.x;
  if (tid < HCHUNKS) {
    const float4* p = (const float4*)h + (size_t)tid * 2;
    float4 v0 = p[0], v1 = p[1];
    float f[8] = {v0.x, v0.y, v0.z, v0.w, v1.x, v1.y, v1.z, v1.w};
    ushortx8 hi, lo;
#pragma unroll
    for (int j = 0; j < 8; j++) {
      unsigned short hj = f2b(f[j]);
      hi[j] = hj;
      lo[j] = f2b(f[j] - b2f(hj));
    }
    ((ushortx8*)h_hi)[tid] = hi;
    ((ushortx8*)h_lo)[tid] = lo;
  } else if (tid < HCHUNKS + 256 * IND) {
    int idx = tid - HCHUNKS;  // output [c][k]
    int c = idx >> 7, k = idx & 127;
    w1t_hi[idx] = f2b(W1[(size_t)k * 256 + c]);
  }
  if (tid < NE) atomicAdd(&counts[dst[tid]], 1);
}

// ---------------- GEMM1 (MFMA, split-A): feat1 = h @ W1 + el1/er1 ----------------
__global__ __launch_bounds__(256) void k_gemm1(const unsigned short* __restrict__ h_hi,
                                               const unsigned short* __restrict__ h_lo,
                                               const unsigned short* __restrict__ w1t_hi,
                                               const float* __restrict__ al,
                                               const float* __restrict__ ar,
                                               unsigned short* __restrict__ feat1b,
                                               float4* __restrict__ el1,
                                               float4* __restrict__ er1) {
  __shared__ unsigned short w1s[256 * IND];  // 64 KB, [col][k] swizzled
  int t = threadIdx.x;
  for (int i = t; i < 4096; i += 256) {  // 4096 ushort8 chunks
    int c = i >> 4, k8 = i & 15;
    ushortx8 v = ((const ushortx8*)w1t_hi)[i];
    int byte = (c * 256 + k8 * 16) ^ ((c & 7) << 4);
    *(ushortx8*)((char*)w1s + byte) = v;
  }
  __syncthreads();
  int w = t >> 6, l = t & 63;
  int c0 = l & 15, kg = l >> 4;
  int rw = blockIdx.x * 64 + w * 16;
  int arow = rw + c0;
  if (arow >= NN) arow = NN - 1;
  const unsigned short* ahp = h_hi + (size_t)arow * IND + kg * 8;
  const unsigned short* alp = h_lo + (size_t)arow * IND + kg * 8;
  f32x4 acc[16] = {};
#pragma unroll
  for (int ks = 0; ks < 4; ks++) {
    bf16x8 ah = *(const bf16x8*)(const void*)(ahp + ks * 32);
    bf16x8 alo = *(const bf16x8*)(const void*)(alp + ks * 32);
#pragma unroll
    for (int n = 0; n < 16; n++) {
      int col = n * 16 + c0;
      int byte = (col * 256 + (ks * 4 + kg) * 16) ^ ((col & 7) << 4);
      bf16x8 b = *(const bf16x8*)(const void*)((const char*)w1s + byte);
      acc[n] = __builtin_amdgcn_mfma_f32_16x16x32_bf16(alo, b, acc[n], 0, 0, 0);
      acc[n] = __builtin_amdgcn_mfma_f32_16x16x32_bf16(ah, b, acc[n], 0, 0, 0);
    }
  }
  float alv[16], arv[16];
#pragma unroll
  for (int n = 0; n < 16; n++) {
    int ai = (n >> 2) * 64 + (n & 3) * 16 + c0;
    alv[n] = al[ai];
    arv[n] = ar[ai];
  }
#pragma unroll
  for (int j = 0; j < 4; j++) {
    int node = rw + kg * 4 + j;
    bool ok = node < NN;
    float pl[4] = {0.f, 0.f, 0.f, 0.f}, pr[4] = {0.f, 0.f, 0.f, 0.f};
#pragma unroll
    for (int n = 0; n < 16; n++) {
      float cv = acc[n][j];
      int hh = n >> 2;
      int d = (n & 3) * 16 + c0;
      if (ok) feat1b[(size_t)node * 256 + d * 4 + hh] = f2b(cv);
      pl[hh] += cv * alv[n];
      pr[hh] += cv * arv[n];
    }
#pragma unroll
    for (int off = 1; off < 16; off <<= 1) {
#pragma unroll
      for (int hh = 0; hh < 4; hh++) {
        pl[hh] += __shfl_xor(pl[hh], off);
        pr[hh] += __shfl_xor(pr[hh], off);
      }
    }
    if (c0 == 0 && ok) {
      el1[node] = make_float4(pl[0], pl[1], pl[2], pl[3]);
      er1[node] = make_float4(pr[0], pr[1], pr[2], pr[3]);
    }
  }
}

// ---------------- hierarchical scan ----------------
#define NSB ((NN + 1023) / 1024)  // 49
__global__ __launch_bounds__(1024) void k_scanA(const int* __restrict__ counts,
                                                int* __restrict__ bsums) {
  int gid = blockIdx.x * 1024 + threadIdx.x;
  int v = (gid < NN) ? counts[gid] : 0;
#pragma unroll
  for (int off = 32; off; off >>= 1) v += __shfl_xor(v, off);
  __shared__ int ws[16];
  int w = threadIdx.x >> 6, l = threadIdx.x & 63;
  if (l == 0) ws[w] = v;
  __syncthreads();
  if (threadIdx.x == 0) {
    int s = 0;
#pragma unroll
    for (int i = 0; i < 16; i++) s += ws[i];
    bsums[blockIdx.x] = s;
  }
}

__global__ __launch_bounds__(64) void k_scanB(const int* __restrict__ bsums,
                                              int* __restrict__ boffs) {
  int l = threadIdx.x;
  int orig = (l < NSB) ? bsums[l] : 0;
  int v = orig;
#pragma unroll
  for (int off = 1; off < 64; off <<= 1) {
    int tv = __shfl_up(v, off);
    if (l >= off) v += tv;
  }
  if (l < NSB) boffs[l] = v - orig;  // exclusive
}

__global__ __launch_bounds__(1024) void k_scanC(const int* __restrict__ counts,
                                                const int* __restrict__ boffs,
                                                int* __restrict__ offs) {
  int gid = blockIdx.x * 1024 + threadIdx.x;
  int orig = (gid < NN) ? counts[gid] : 0;
  int v = orig;
  int w = threadIdx.x >> 6, l = threadIdx.x & 63;
#pragma unroll
  for (int off = 1; off < 64; off <<= 1) {
    int tv = __shfl_up(v, off);
    if (l >= off) v += tv;
  }
  __shared__ int ws[16];
  if (l == 63) ws[w] = v;
  __syncthreads();
  int woff = 0;
#pragma unroll
  for (int i = 0; i < 16; i++)
    if (i < w) woff += ws[i];
  if (gid < NN) offs[gid] = boffs[blockIdx.x] + woff + v - orig;
  if (gid == 0) offs[NN] = NE;
}

__global__ void k_scatter(const int* __restrict__ src, const int* __restrict__ dst,
                          const int* __restrict__ offs, int* __restrict__ cursor,
                          int* __restrict__ srcs) {
  int e = blockIdx.x * blockDim.x + threadIdx.x;
  if (e >= NE) return;
  int d = dst[e];
  int p = atomicAdd(&cursor[d], 1);
  srcs[offs[d] + p] = src[e];
}

// ---------------- aggregation layer 1 ----------------
__global__ __launch_bounds__(256) void k_agg1(const int* __restrict__ offs, const int* __restrict__ srcs,
                                              const float4* __restrict__ el1, const float4* __restrict__ er1,
                                              const ushort4* __restrict__ feat1b,
                                              const float* __restrict__ b1,
                                              unsigned short* __restrict__ x1b) {
  int wid = (blockIdx.x * 256 + threadIdx.x) >> 6;
  int lane = threadIdx.x & 63;
  if (wid >= NN) return;
  int i = offs[wid], end = offs[wid + 1];
  float4 er = er1[wid];
  float a0 = 0, a1 = 0, a2 = 0, a3 = 0, d0 = 0, d1 = 0, d2 = 0, d3 = 0;
  for (; i + 2 <= end; i += 2) {
    int s0 = srcs[i], s1 = srcs[i + 1];
    float4 l0 = el1[s0], l1 = el1[s1];
    ushort4 f0 = feat1b[(size_t)s0 * 64 + lane];
    ushort4 f1 = feat1b[(size_t)s1 * 64 + lane];
    float w0x = __expf(lrelu(l0.x + er.x)), w0y = __expf(lrelu(l0.y + er.y));
    float w0z = __expf(lrelu(l0.z + er.z)), w0w = __expf(lrelu(l0.w + er.w));
    float w1x = __expf(lrelu(l1.x + er.x)), w1y = __expf(lrelu(l1.y + er.y));
    float w1z = __expf(lrelu(l1.z + er.z)), w1w = __expf(lrelu(l1.w + er.w));
    a0 += w0x * b2f(f0.x) + w1x * b2f(f1.x);
    a1 += w0y * b2f(f0.y) + w1y * b2f(f1.y);
    a2 += w0z * b2f(f0.z) + w1z * b2f(f1.z);
    a3 += w0w * b2f(f0.w) + w1w * b2f(f1.w);
    d0 += w0x + w1x; d1 += w0y + w1y; d2 += w0z + w1z; d3 += w0w + w1w;
  }
  if (i < end) {
    int s0 = srcs[i];
    float4 l0 = el1[s0];
    ushort4 f0 = feat1b[(size_t)s0 * 64 + lane];
    float w0x = __expf(lrelu(l0.x + er.x)), w0y = __expf(lrelu(l0.y + er.y));
    float w0z = __expf(lrelu(l0.z + er.z)), w0w = __expf(lrelu(l0.w + er.w));
    a0 += w0x * b2f(f0.x); a1 += w0y * b2f(f0.y);
    a2 += w0z * b2f(f0.z); a3 += w0w * b2f(f0.w);
    d0 += w0x; d1 += w0y; d2 += w0z; d3 += w0w;
  }
  size_t base = (size_t)wid * 256;
  x1b[base + lane]        = f2b(fmaxf(a0 / fmaxf(d0, 1e-9f) + b1[lane], 0.f));
  x1b[base + 64 + lane]   = f2b(fmaxf(a1 / fmaxf(d1, 1e-9f) + b1[64 + lane], 0.f));
  x1b[base + 128 + lane]  = f2b(fmaxf(a2 / fmaxf(d2, 1e-9f) + b1[128 + lane], 0.f));
  x1b[base + 192 + lane]  = f2b(fmaxf(a3 / fmaxf(d3, 1e-9f) + b1[192 + lane], 0.f));
}

// ---------------- GEMM2 (MFMA bf16) ----------------
__global__ __launch_bounds__(256) void k_gemm2(const unsigned short* __restrict__ x1b,
                                               const float* __restrict__ W2,
                                               const float* __restrict__ al2,
                                               const float* __restrict__ ar2,
                                               unsigned short* __restrict__ feat2b,
                                               float* __restrict__ el2,
                                               float* __restrict__ er2) {
  __shared__ unsigned short w2t[64 * 256];  // 32 KB, [col][k] swizzled
  int t = threadIdx.x;
  for (int i = t; i < 64 * 256; i += 256) {
    int k = i >> 6, col = i & 63;
    int kg = k >> 3;
    int s = (col * 32 + kg) ^ (col & 7);
    w2t[s * 8 + (k & 7)] = f2b(W2[i]);
  }
  __syncthreads();
  int w = t >> 6, l = t & 63;
  int rw = blockIdx.x * 64 + w * 16;
  int arow = rw + (l & 15);
  if (arow >= NN) arow = NN - 1;
  const unsigned short* aptr = x1b + (size_t)arow * 256 + (l >> 4) * 8;
  f32x4 acc[4] = {};
#pragma unroll
  for (int ks = 0; ks < 8; ks++) {
    bf16x8 a = *(const bf16x8*)(const void*)(aptr + ks * 32);
#pragma unroll
    for (int n = 0; n < 4; n++) {
      int colg = n * 16 + (l & 15);
      int kg = ks * 4 + (l >> 4);
      int s = (colg * 32 + kg) ^ (colg & 7);
      bf16x8 b = *(const bf16x8*)(const void*)&w2t[s * 8];
      acc[n] = __builtin_amdgcn_mfma_f32_16x16x32_bf16(a, b, acc[n], 0, 0, 0);
    }
  }
  float al2v[4], ar2v[4];
#pragma unroll
  for (int n = 0; n < 4; n++) { al2v[n] = al2[n * 16 + (l & 15)]; ar2v[n] = ar2[n * 16 + (l & 15)]; }
#pragma unroll
  for (int j = 0; j < 4; j++) {
    int node = rw + (l >> 4) * 4 + j;
    float pl = 0.f, pr = 0.f;
#pragma unroll
    for (int n = 0; n < 4; n++) {
      float c = acc[n][j];
      if (node < NN) feat2b[(size_t)node * 64 + n * 16 + (l & 15)] = f2b(c);
      pl += c * al2v[n];
      pr += c * ar2v[n];
    }
#pragma unroll
    for (int off = 1; off < 16; off <<= 1) {
      pl += __shfl_xor(pl, off);
      pr += __shfl_xor(pr, off);
    }
    if ((l & 15) == 0 && node < NN) { el2[node] = pl; er2[node] = pr; }
  }
}

// ---------------- aggregation layer 2 + fused mean-pool atomics ----------------
__global__ __launch_bounds__(256) void k_agg2(const int* __restrict__ offs, const int* __restrict__ srcs,
                                              const float* __restrict__ el2, const float* __restrict__ er2,
                                              const unsigned short* __restrict__ feat2b,
                                              const float* __restrict__ b2, const int* __restrict__ gid,
                                              float* __restrict__ psum) {
  int wid = (blockIdx.x * 256 + threadIdx.x) >> 6;
  int lane = threadIdx.x & 63;
  if (wid >= NN) return;
  int i = offs[wid], end = offs[wid + 1];
  float erv = er2[wid];
  float acc = 0.f, dsum = 0.f;
  for (; i + 2 <= end; i += 2) {
    int s0 = srcs[i], s1 = srcs[i + 1];
    float w0 = __expf(lrelu(el2[s0] + erv));
    float w1 = __expf(lrelu(el2[s1] + erv));
    float f0 = b2f(feat2b[(size_t)s0 * 64 + lane]);
    float f1 = b2f(feat2b[(size_t)s1 * 64 + lane]);
    acc += w0 * f0 + w1 * f1;
    dsum += w0 + w1;
  }
  if (i < end) {
    int s0 = srcs[i];
    float w0 = __expf(lrelu(el2[s0] + erv));
    acc += w0 * b2f(feat2b[(size_t)s0 * 64 + lane]);
    dsum += w0;
  }
  float v = fmaxf(acc / fmaxf(dsum, 1e-9f) + b2[lane], 0.f);
  atomicAdd(&psum[gid[wid] * 64 + lane], v);
}

// ---------------- classifier head ----------------
__global__ __launch_bounds__(256) void k_head(const float* __restrict__ psum, const int* __restrict__ gid,
                                              const float* __restrict__ Wc, const float* __restrict__ bc,
                                              float* __restrict__ out) {
  int wid = (blockIdx.x * 256 + threadIdx.x) >> 6;
  int lane = threadIdx.x & 63;
  if (wid >= NG) return;
  int g = wid;
  int lo = 0, hi = NN;
  while (lo < hi) { int mid = (lo + hi) >> 1; if (gid[mid] < g) lo = mid + 1; else hi = mid; }
  int lb = lo;
  hi = NN;
  while (lo < hi) { int mid = (lo + hi) >> 1; if (gid[mid] < g + 1) lo = mid + 1; else hi = mid; }
  int cnt = lo - lb;
  float inv = 1.f / fmaxf((float)cnt, 1.f);
  float p = psum[g * 64 + lane] * inv;
  float a0 = p * Wc[lane * 2 + 0];
  float a1 = p * Wc[lane * 2 + 1];
#pragma unroll
  for (int off = 32; off; off >>= 1) { a0 += __shfl_xor(a0, off); a1 += __shfl_xor(a1, off); }
  if (lane == 0) { out[g * 2 + 0] = a0 + bc[0]; out[g * 2 + 1] = a1 + bc[1]; }
}

extern "C" void kernel_launch(void* const* d_in, const int* in_sizes, int n_in,
                              void* d_out, int out_size, void* d_ws, size_t ws_size,
                              hipStream_t stream) {
  const float* h = (const float*)d_in[0];
  const int* src = (const int*)d_in[1];
  const int* dst = (const int*)d_in[2];
  const int* gid = (const int*)d_in[3];
  const float* W1 = (const float*)d_in[4];
  const float* al1 = (const float*)d_in[5];
  const float* ar1 = (const float*)d_in[6];
  const float* b1 = (const float*)d_in[7];
  const float* W2 = (const float*)d_in[8];
  const float* al2 = (const float*)d_in[9];
  const float* ar2 = (const float*)d_in[10];
  const float* b2 = (const float*)d_in[11];
  const float* Wc = (const float*)d_in[12];
  const float* bc = (const float*)d_in[13];
  float* out = (float*)d_out;

  char* wsp = (char*)d_ws;
  size_t off = 0;
  auto take = [&](size_t bytes) -> void* {
    void* p = wsp + off;
    off = (off + bytes + 255) & ~(size_t)255;
    return p;
  };
  unsigned short* feat1b = (unsigned short*)take((size_t)NN * 256 * 2);   // 25.6 MB
  unsigned short* x1b = (unsigned short*)take((size_t)NN * 256 * 2);      // 25.6 MB
  unsigned short* feat2b = (unsigned short*)take((size_t)NN * 64 * 2);    // 6.4 MB
  unsigned short* h_hi = (unsigned short*)take((size_t)NN * IND * 2);     // 12.8 MB
  unsigned short* h_lo = (unsigned short*)take((size_t)NN * IND * 2);     // 12.8 MB
  unsigned short* w1t_hi = (unsigned short*)take((size_t)256 * IND * 2);  // 64 KB
  float4* el1 = (float4*)take((size_t)NN * 16);
  float4* er1 = (float4*)take((size_t)NN * 16);
  float* el2 = (float*)take((size_t)NN * 4);
  float* er2 = (float*)take((size_t)NN * 4);
  int* counts = (int*)take((size_t)NN * 4);
  int* offs = (int*)take((size_t)(NN + 1) * 4);
  int* cursor = (int*)take((size_t)NN * 4);
  int* srcs = (int*)take((size_t)NE * 4);
  float* psum = (float*)take((size_t)NG * 64 * 4);
  int* bsums = (int*)take((size_t)NSB * 4);
  int* boffs = (int*)take((size_t)NSB * 4);

  hipMemsetAsync(counts, 0, (size_t)NN * 4, stream);
  hipMemsetAsync(cursor, 0, (size_t)NN * 4, stream);
  hipMemsetAsync(psum, 0, (size_t)NG * 64 * 4, stream);

  // prep (h split + W1 transpose + edge count)
  k_prep<<<(HCHUNKS + 256 * IND + 255) / 256, 256, 0, stream>>>(h, W1, dst, h_hi, h_lo, w1t_hi, counts);

  // hierarchical scan + scatter
  k_scanA<<<NSB, 1024, 0, stream>>>(counts, bsums);
  k_scanB<<<1, 64, 0, stream>>>(bsums, boffs);
  k_scanC<<<NSB, 1024, 0, stream>>>(counts, boffs, offs);
  k_scatter<<<(NE + 255) / 256, 256, 0, stream>>>(src, dst, offs, cursor, srcs);

  // layer 1
  k_gemm1<<<(NN + 63) / 64, 256, 0, stream>>>(h_hi, h_lo, w1t_hi, al1, ar1, feat1b, el1, er1);
  k_agg1<<<(NN * 64 + 255) / 256, 256, 0, stream>>>(offs, srcs, el1, er1, (const ushort4*)feat1b, b1, x1b);

  // layer 2
  k_gemm2<<<(NN + 63) / 64, 256, 0, stream>>>(x1b, W2, al2, ar2, feat2b, el2, er2);
  k_agg2<<<(NN * 64 + 255) / 256, 256, 0, stream>>>(offs, srcs, el2, er2, feat2b, b2, gid, psum);

  // head
  k_head<<<(NG * 64 + 255) / 256, 256, 0, stream>>>(psum, gid, Wc, bc, out);
}